// Round 1
// baseline (1365.385 us; speedup 1.0000x reference)
//
#include <hip/hip_runtime.h>

#define OBS 17
#define ACT 4
#define HID 64

// ws layout (floats):
// [0..15]  Qinv (row-major 4x4)
// [16..19] logstd
// [20..23] inv_std = 1/exp(logstd)
// [24]     entropy (uniform across rows)
// [25]     s0
// [26]     sum(logstd) + 2*log(2*pi)   (log_prob constant term)

__device__ __forceinline__ float fast_tanh(float v) {
    // tanh(v) = 1 - 2/(1+exp(2v)); exact at +/-inf saturation, ~1e-7 abs err
    float e = __expf(2.0f * v);
    return 1.0f - 2.0f / (e + 1.0f);
}

__global__ void prep_kernel(const float* __restrict__ L,
                            const float* __restrict__ logstd,
                            const float* __restrict__ s0,
                            float* __restrict__ ws) {
    if (threadIdx.x != 0 || blockIdx.x != 0) return;
    const float LOG2PI = 1.8378770664093453f;
    // Q = tril(L) @ tril(L)^T + 1e-4*I
    float Q[4][4];
    for (int a = 0; a < 4; ++a) {
        for (int b = 0; b < 4; ++b) {
            float s = (a == b) ? 1e-4f : 0.0f;
            int m = a < b ? a : b;
            for (int k = 0; k <= m; ++k) s += L[a * 4 + k] * L[b * 4 + k];
            Q[a][b] = s;
        }
    }
    // Gauss-Jordan inverse (SPD, no pivoting needed)
    float M[4][8];
    for (int a = 0; a < 4; ++a) {
        for (int b = 0; b < 4; ++b) {
            M[a][b] = Q[a][b];
            M[a][4 + b] = (a == b) ? 1.0f : 0.0f;
        }
    }
    for (int c = 0; c < 4; ++c) {
        float inv = 1.0f / M[c][c];
        for (int j = 0; j < 8; ++j) M[c][j] *= inv;
        for (int r = 0; r < 4; ++r) {
            if (r == c) continue;
            float f = M[r][c];
            for (int j = 0; j < 8; ++j) M[r][j] -= f * M[c][j];
        }
    }
    for (int a = 0; a < 4; ++a)
        for (int b = 0; b < 4; ++b) ws[a * 4 + b] = M[a][4 + b];

    float ent = 0.0f, lsum = 0.0f;
    for (int a = 0; a < 4; ++a) {
        float ls = logstd[a];
        ws[16 + a] = ls;
        ws[20 + a] = 1.0f / __expf(ls);
        ent += 0.5f + 0.5f * LOG2PI + ls;
        lsum += ls;
    }
    ws[24] = ent;
    ws[25] = s0[0];
    ws[26] = lsum + 2.0f * LOG2PI;
}

__global__ __launch_bounds__(256) void fused_kernel(
    const float* __restrict__ X, const float* __restrict__ sdfs,
    const float* __restrict__ grads, const float* __restrict__ fx,
    const float* __restrict__ gx, const float* __restrict__ act,
    const float* __restrict__ cW1, const float* __restrict__ cb1,
    const float* __restrict__ cW2, const float* __restrict__ cb2,
    const float* __restrict__ cW3, const float* __restrict__ cb3,
    const float* __restrict__ aW1, const float* __restrict__ ab1,
    const float* __restrict__ aW2, const float* __restrict__ ab2,
    const float* __restrict__ aW3, const float* __restrict__ ab3,
    const float* __restrict__ ws, float* __restrict__ out, int N) {
    int i = blockIdx.x * blockDim.x + threadIdx.x;
    if (i >= N) return;

    // ---- load observation (cache-friendly; wave covers a contiguous 4.3KB span)
    float x[OBS];
#pragma unroll
    for (int k = 0; k < OBS; ++k) x[k] = X[i * OBS + k];

    float h1[HID];
    float h2[HID];

    // ================= actor MLP =================
    // NOTE: all loops indexing h1/h2 are FULLY unrolled so every array index is
    // compile-time (runtime-indexed register arrays go to scratch on gfx950).
#pragma unroll
    for (int j = 0; j < HID; ++j) {
        float acc = ab1[j];
#pragma unroll
        for (int k = 0; k < OBS; ++k) acc = fmaf(x[k], aW1[k * HID + j], acc);
        h1[j] = fast_tanh(acc);
    }
#pragma unroll
    for (int j = 0; j < HID; ++j) {
        float acc = ab2[j];
#pragma unroll
        for (int k = 0; k < HID; ++k) acc = fmaf(h1[k], aW2[k * HID + j], acc);
        h2[j] = fast_tanh(acc);
    }
    float mean0 = ab3[0], mean1 = ab3[1], mean2 = ab3[2], mean3 = ab3[3];
#pragma unroll
    for (int k = 0; k < HID; ++k) {
        mean0 = fmaf(h2[k], aW3[k * ACT + 0], mean0);
        mean1 = fmaf(h2[k], aW3[k * ACT + 1], mean1);
        mean2 = fmaf(h2[k], aW3[k * ACT + 2], mean2);
        mean3 = fmaf(h2[k], aW3[k * ACT + 3], mean3);
    }

    // ================= critic MLP (reuse h1/h2) =================
#pragma unroll
    for (int j = 0; j < HID; ++j) {
        float acc = cb1[j];
#pragma unroll
        for (int k = 0; k < OBS; ++k) acc = fmaf(x[k], cW1[k * HID + j], acc);
        h1[j] = fast_tanh(acc);
    }
#pragma unroll
    for (int j = 0; j < HID; ++j) {
        float acc = cb2[j];
#pragma unroll
        for (int k = 0; k < HID; ++k) acc = fmaf(h1[k], cW2[k * HID + j], acc);
        h2[j] = fast_tanh(acc);
    }
    float value = cb3[0];
#pragma unroll
    for (int k = 0; k < HID; ++k) value = fmaf(h2[k], cW3[k], value);

    // ================= CBF-QP =================
    // G[a] = -sum_s grads[s]*g_x[s][a];  gf = grads . f_x
    float G0 = 0.f, G1 = 0.f, G2 = 0.f, G3 = 0.f, gf = 0.f;
    const float* gxr = gx + (size_t)i * (OBS * ACT);
#pragma unroll
    for (int s = 0; s < OBS; ++s) {
        float gr = grads[i * OBS + s];
        gf = fmaf(gr, fx[i * OBS + s], gf);
        G0 = fmaf(-gr, gxr[s * 4 + 0], G0);
        G1 = fmaf(-gr, gxr[s * 4 + 1], G1);
        G2 = fmaf(-gr, gxr[s * 4 + 2], G2);
        G3 = fmaf(-gr, gxr[s * 4 + 3], G3);
    }
    float a0 = act[i * 4 + 0], a1 = act[i * 4 + 1];
    float a2 = act[i * 4 + 2], a3 = act[i * 4 + 3];
    // h = s0 + alpha*sdfs + grads.f_x + grads.g_x.action; last term == -G.action
    float h = ws[25] + sdfs[i] + gf - (G0 * a0 + G1 * a1 + G2 * a2 + G3 * a3);

    float v0 = ws[0] * G0 + ws[1] * G1 + ws[2] * G2 + ws[3] * G3;
    float v1 = ws[4] * G0 + ws[5] * G1 + ws[6] * G2 + ws[7] * G3;
    float v2 = ws[8] * G0 + ws[9] * G1 + ws[10] * G2 + ws[11] * G3;
    float v3 = ws[12] * G0 + ws[13] * G1 + ws[14] * G2 + ws[15] * G3;
    float denom = G0 * v0 + G1 * v1 + G2 * v2 + G3 * v3;
    float lam = fmaxf(0.0f, -h / denom);

    float u0 = mean0 - lam * v0;
    float u1 = mean1 - lam * v1;
    float u2 = mean2 - lam * v2;
    float u3 = mean3 - lam * v3;

    // ================= log_prob =================
    float z0 = (a0 - mean0) * ws[20];
    float z1 = (a1 - mean1) * ws[21];
    float z2 = (a2 - mean2) * ws[22];
    float z3 = (a3 - mean3) * ws[23];
    float lp = -0.5f * (z0 * z0 + z1 * z1 + z2 * z2 + z3 * z3) - ws[26];

    // ================= stores =================
    reinterpret_cast<float4*>(out)[i] = make_float4(u0, u1, u2, u3);
    out[4 * N + i] = lp;
    out[5 * N + i] = ws[24];  // entropy (uniform)
    out[6 * N + i] = value;
}

extern "C" void kernel_launch(void* const* d_in, const int* in_sizes, int n_in,
                              void* d_out, int out_size, void* d_ws, size_t ws_size,
                              hipStream_t stream) {
    const float* X     = (const float*)d_in[0];
    const float* sdfs  = (const float*)d_in[1];
    const float* grads = (const float*)d_in[2];
    const float* fx    = (const float*)d_in[3];
    const float* gx    = (const float*)d_in[4];
    const float* act   = (const float*)d_in[5];
    const float* cW1   = (const float*)d_in[6];
    const float* cb1   = (const float*)d_in[7];
    const float* cW2   = (const float*)d_in[8];
    const float* cb2   = (const float*)d_in[9];
    const float* cW3   = (const float*)d_in[10];
    const float* cb3   = (const float*)d_in[11];
    const float* aW1   = (const float*)d_in[12];
    const float* ab1   = (const float*)d_in[13];
    const float* aW2   = (const float*)d_in[14];
    const float* ab2   = (const float*)d_in[15];
    const float* aW3   = (const float*)d_in[16];
    const float* ab3   = (const float*)d_in[17];
    const float* logstd = (const float*)d_in[18];
    const float* L     = (const float*)d_in[19];
    const float* s0    = (const float*)d_in[20];

    float* out = (float*)d_out;
    float* ws  = (float*)d_ws;

    int N = in_sizes[0] / OBS;

    hipLaunchKernelGGL(prep_kernel, dim3(1), dim3(64), 0, stream, L, logstd, s0, ws);
    int blocks = (N + 255) / 256;
    hipLaunchKernelGGL(fused_kernel, dim3(blocks), dim3(256), 0, stream,
                       X, sdfs, grads, fx, gx, act,
                       cW1, cb1, cW2, cb2, cW3, cb3,
                       aW1, ab1, aW2, ab2, aW3, ab3,
                       ws, out, N);
}

// Round 6
// 336.087 us; speedup vs baseline: 4.0626x; 4.0626x over previous
//
#include <hip/hip_runtime.h>

#define OBS 17
#define ACT 4
#define HID 64
#define BLK 128

// ws layout (floats):
// [0..15]  Qinv (row-major 4x4)
// [16..19] logstd
// [20..23] inv_std = 1/exp(logstd)
// [24]     entropy (uniform across rows)
// [25]     s0
// [26]     sum(logstd) + 2*log(2*pi)   (log_prob constant term)

__device__ __forceinline__ float fast_tanh(float v) {
    // tanh(v) = 1 - 2/(1+exp(2v)); exact saturation at +/-inf, ~1e-7 abs err
    float e = __expf(2.0f * v);
    return 1.0f - 2.0f / (e + 1.0f);
}

__global__ void prep_kernel(const float* __restrict__ L,
                            const float* __restrict__ logstd,
                            const float* __restrict__ s0,
                            float* __restrict__ ws) {
    if (threadIdx.x != 0 || blockIdx.x != 0) return;
    const float LOG2PI = 1.8378770664093453f;
    // Q = tril(L) @ tril(L)^T + 1e-4*I
    float Q[4][4];
    for (int a = 0; a < 4; ++a) {
        for (int b = 0; b < 4; ++b) {
            float s = (a == b) ? 1e-4f : 0.0f;
            int m = a < b ? a : b;
            for (int k = 0; k <= m; ++k) s += L[a * 4 + k] * L[b * 4 + k];
            Q[a][b] = s;
        }
    }
    // Gauss-Jordan inverse (SPD)
    float M[4][8];
    for (int a = 0; a < 4; ++a) {
        for (int b = 0; b < 4; ++b) {
            M[a][b] = Q[a][b];
            M[a][4 + b] = (a == b) ? 1.0f : 0.0f;
        }
    }
    for (int c = 0; c < 4; ++c) {
        float inv = 1.0f / M[c][c];
        for (int j = 0; j < 8; ++j) M[c][j] *= inv;
        for (int r = 0; r < 4; ++r) {
            if (r == c) continue;
            float f = M[r][c];
            for (int j = 0; j < 8; ++j) M[r][j] -= f * M[c][j];
        }
    }
    for (int a = 0; a < 4; ++a)
        for (int b = 0; b < 4; ++b) ws[a * 4 + b] = M[a][4 + b];

    float ent = 0.0f, lsum = 0.0f;
    for (int a = 0; a < 4; ++a) {
        float ls = logstd[a];
        ws[16 + a] = ls;
        ws[20 + a] = 1.0f / __expf(ls);
        ent += 0.5f + 0.5f * LOG2PI + ls;
        lsum += ls;
    }
    ws[24] = ent;
    ws[25] = s0[0];
    ws[26] = lsum + 2.0f * LOG2PI;
}

__global__ __launch_bounds__(BLK, 2) void fused_kernel(
    const float* __restrict__ X, const float* __restrict__ sdfs,
    const float* __restrict__ grads, const float* __restrict__ fx,
    const float* __restrict__ gx, const float* __restrict__ act,
    const float* __restrict__ cW1, const float* __restrict__ cb1,
    const float* __restrict__ cW2, const float* __restrict__ cb2,
    const float* __restrict__ cW3, const float* __restrict__ cb3,
    const float* __restrict__ aW1, const float* __restrict__ ab1,
    const float* __restrict__ aW2, const float* __restrict__ ab2,
    const float* __restrict__ aW3, const float* __restrict__ ab3,
    const float* __restrict__ ws, float* __restrict__ out, int N) {
    // Per-thread LDS column for hidden layer 1: thread t only ever touches
    // hs[*][t] -> no cross-thread sharing, no barriers, no bank conflicts
    // (64 lanes at stride 4B = 2 lanes/bank = free).
    __shared__ float hs[HID][BLK];  // 32 KB

    const int tid = threadIdx.x;
    const int i = blockIdx.x * BLK + tid;
    if (i >= N) return;

    // ---- observation in registers (compile-time indexed only)
    float x[OBS];
#pragma unroll
    for (int k = 0; k < OBS; ++k) x[k] = X[i * OBS + k];

    float acc[64];  // the ONLY big register array; reused 4x (a/c layer1, layer2)

    // ================= actor =================
#pragma unroll
    for (int j = 0; j < HID; ++j) acc[j] = ab1[j];
#pragma unroll
    for (int k = 0; k < OBS; ++k) {
        float xk = x[k];
#pragma unroll
        for (int j = 0; j < HID; ++j) acc[j] = fmaf(xk, aW1[k * HID + j], acc[j]);
    }
#pragma unroll
    for (int j = 0; j < HID; ++j) hs[j][tid] = fast_tanh(acc[j]);

#pragma unroll
    for (int j = 0; j < HID; ++j) acc[j] = ab2[j];
#pragma unroll 4
    for (int k = 0; k < HID; ++k) {  // rolled: h1 read from LDS (runtime k OK)
        float hk = hs[k][tid];
#pragma unroll
        for (int j = 0; j < HID; ++j) acc[j] = fmaf(hk, aW2[k * HID + j], acc[j]);
    }
    float mean0 = ab3[0], mean1 = ab3[1], mean2 = ab3[2], mean3 = ab3[3];
#pragma unroll
    for (int k = 0; k < HID; ++k) {
        float t = fast_tanh(acc[k]);
        mean0 = fmaf(t, aW3[k * ACT + 0], mean0);
        mean1 = fmaf(t, aW3[k * ACT + 1], mean1);
        mean2 = fmaf(t, aW3[k * ACT + 2], mean2);
        mean3 = fmaf(t, aW3[k * ACT + 3], mean3);
    }

    // ================= critic =================
#pragma unroll
    for (int j = 0; j < HID; ++j) acc[j] = cb1[j];
#pragma unroll
    for (int k = 0; k < OBS; ++k) {
        float xk = x[k];
#pragma unroll
        for (int j = 0; j < HID; ++j) acc[j] = fmaf(xk, cW1[k * HID + j], acc[j]);
    }
#pragma unroll
    for (int j = 0; j < HID; ++j) hs[j][tid] = fast_tanh(acc[j]);

#pragma unroll
    for (int j = 0; j < HID; ++j) acc[j] = cb2[j];
#pragma unroll 4
    for (int k = 0; k < HID; ++k) {
        float hk = hs[k][tid];
#pragma unroll
        for (int j = 0; j < HID; ++j) acc[j] = fmaf(hk, cW2[k * HID + j], acc[j]);
    }
    float value = cb3[0];
#pragma unroll
    for (int k = 0; k < HID; ++k) value = fmaf(fast_tanh(acc[k]), cW3[k], value);

    // ================= CBF-QP =================
    float G0 = 0.f, G1 = 0.f, G2 = 0.f, G3 = 0.f, gf = 0.f;
    const float* gxr = gx + (size_t)i * (OBS * ACT);
#pragma unroll
    for (int s = 0; s < OBS; ++s) {
        float gr = grads[i * OBS + s];
        gf = fmaf(gr, fx[i * OBS + s], gf);
        G0 = fmaf(-gr, gxr[s * 4 + 0], G0);
        G1 = fmaf(-gr, gxr[s * 4 + 1], G1);
        G2 = fmaf(-gr, gxr[s * 4 + 2], G2);
        G3 = fmaf(-gr, gxr[s * 4 + 3], G3);
    }
    float a0 = act[i * 4 + 0], a1 = act[i * 4 + 1];
    float a2 = act[i * 4 + 2], a3 = act[i * 4 + 3];
    // h = s0 + alpha*sdfs + grads.f_x + grads.g_x.action; last term == -G.action
    float h = ws[25] + sdfs[i] + gf - (G0 * a0 + G1 * a1 + G2 * a2 + G3 * a3);

    float v0 = ws[0] * G0 + ws[1] * G1 + ws[2] * G2 + ws[3] * G3;
    float v1 = ws[4] * G0 + ws[5] * G1 + ws[6] * G2 + ws[7] * G3;
    float v2 = ws[8] * G0 + ws[9] * G1 + ws[10] * G2 + ws[11] * G3;
    float v3 = ws[12] * G0 + ws[13] * G1 + ws[14] * G2 + ws[15] * G3;
    float denom = G0 * v0 + G1 * v1 + G2 * v2 + G3 * v3;
    float lam = fmaxf(0.0f, -h / denom);

    float u0 = mean0 - lam * v0;
    float u1 = mean1 - lam * v1;
    float u2 = mean2 - lam * v2;
    float u3 = mean3 - lam * v3;

    // ================= log_prob =================
    float z0 = (a0 - mean0) * ws[20];
    float z1 = (a1 - mean1) * ws[21];
    float z2 = (a2 - mean2) * ws[22];
    float z3 = (a3 - mean3) * ws[23];
    float lp = -0.5f * (z0 * z0 + z1 * z1 + z2 * z2 + z3 * z3) - ws[26];

    // ================= stores =================
    reinterpret_cast<float4*>(out)[i] = make_float4(u0, u1, u2, u3);
    out[4 * N + i] = lp;
    out[5 * N + i] = ws[24];  // entropy (uniform)
    out[6 * N + i] = value;
}

extern "C" void kernel_launch(void* const* d_in, const int* in_sizes, int n_in,
                              void* d_out, int out_size, void* d_ws, size_t ws_size,
                              hipStream_t stream) {
    const float* X     = (const float*)d_in[0];
    const float* sdfs  = (const float*)d_in[1];
    const float* grads = (const float*)d_in[2];
    const float* fx    = (const float*)d_in[3];
    const float* gx    = (const float*)d_in[4];
    const float* act   = (const float*)d_in[5];
    const float* cW1   = (const float*)d_in[6];
    const float* cb1   = (const float*)d_in[7];
    const float* cW2   = (const float*)d_in[8];
    const float* cb2   = (const float*)d_in[9];
    const float* cW3   = (const float*)d_in[10];
    const float* cb3   = (const float*)d_in[11];
    const float* aW1   = (const float*)d_in[12];
    const float* ab1   = (const float*)d_in[13];
    const float* aW2   = (const float*)d_in[14];
    const float* ab2   = (const float*)d_in[15];
    const float* aW3   = (const float*)d_in[16];
    const float* ab3   = (const float*)d_in[17];
    const float* logstd = (const float*)d_in[18];
    const float* L     = (const float*)d_in[19];
    const float* s0    = (const float*)d_in[20];

    float* out = (float*)d_out;
    float* ws  = (float*)d_ws;

    int N = in_sizes[0] / OBS;

    hipLaunchKernelGGL(prep_kernel, dim3(1), dim3(64), 0, stream, L, logstd, s0, ws);
    int blocks = (N + BLK - 1) / BLK;
    hipLaunchKernelGGL(fused_kernel, dim3(blocks), dim3(BLK), 0, stream,
                       X, sdfs, grads, fx, gx, act,
                       cW1, cb1, cW2, cb2, cW3, cb3,
                       aW1, ab1, aW2, ab2, aW3, ab3,
                       ws, out, N);
}